// Round 5
// baseline (6520.695 us; speedup 1.0000x reference)
//
#include <hip/hip_runtime.h>
#include <hip/hip_bf16.h>

// Eikonal3D: 64^3 grid, 128 Jacobi Godunov sweeps = 32 phases x 4 fused
// iterations (k=4 temporal blocking, 8^3 tiles, 16^3 halo regions).
// Round 4: low-VGPR phase body (sequential per-chunk updates, no full unroll)
// + persistent cooperative kernel (grid barrier) with runtime fallback to the
// multi-launch path if hipLaunchCooperativeKernel is rejected.
// n_iter fixed at 128 by setup_inputs (host must know phase count).

#define NPTS (64 * 64 * 64)
#define BIGV 1000.0f
#define PADV 10000.0f   // BIG*10 pad value
#define NEV 4096
#define NTILE 512       // 8^3 tiles of 8^3 cells
#define NPH 32          // 128 / 4

__device__ __forceinline__ float godunov_cell(float uc, float ax, float ay,
                                              float az, float f) {
    float lo = fminf(ax, ay), hi = fmaxf(ax, ay);
    float a1 = fminf(lo, az);
    float a3 = fmaxf(hi, az);
    float a2 = fminf(fmaxf(lo, az), hi);
    float x1 = a1 + f;
    float d12 = a1 - a2;
    float d2 = 2.0f * f * f - d12 * d12;
    float x2 = 0.5f * (a1 + a2 + sqrtf(fmaxf(d2, 0.0f)));
    float s = a1 + a2 + a3;
    float q = a1 * a1 + a2 * a2 + a3 * a3;
    float d3 = s * s - 3.0f * (q - f * f);
    float x3 = (s + sqrtf(fmaxf(d3, 0.0f))) * (1.0f / 3.0f);
    float unew = (x1 <= a2) ? x1 : ((x2 <= a3) ? x2 : x3);
    return fminf(uc, unew);
}

// one z-chunk (4 cells) Jacobi update; merge via per-element z-range mask
__device__ __forceinline__ float4 upd_chunk(float4 cc, float4 xm, float4 xp,
                                            float4 ym, float4 yp,
                                            float zprev, float znext, float4 f,
                                            int zb, int zlo, int zhi) {
    float n0 = godunov_cell(cc.x, fminf(xm.x, xp.x), fminf(ym.x, yp.x), fminf(zprev, cc.y), f.x);
    float n1 = godunov_cell(cc.y, fminf(xm.y, xp.y), fminf(ym.y, yp.y), fminf(cc.x, cc.z), f.y);
    float n2 = godunov_cell(cc.z, fminf(xm.z, xp.z), fminf(ym.z, yp.z), fminf(cc.y, cc.w), f.z);
    float n3 = godunov_cell(cc.w, fminf(xm.w, xp.w), fminf(ym.w, yp.w), fminf(cc.z, znext), f.w);
    float4 r;
    r.x = (zb + 0 >= zlo && zb + 0 <= zhi) ? n0 : cc.x;
    r.y = (zb + 1 >= zlo && zb + 1 <= zhi) ? n1 : cc.y;
    r.z = (zb + 2 >= zlo && zb + 2 <= zhi) ? n2 : cc.z;
    r.w = (zb + 3 >= zlo && zb + 3 <= zhi) ? n3 : cc.w;
    return r;
}

// processes one 8^3 tile (16^3 halo region), 4 fused Jacobi iterations.
// Uniform control flow per block; small register live-set by sequential chunks.
__device__ __forceinline__ void process_tile(
    const int tile, const int t,
    const float* __restrict__ src, float* __restrict__ dst,
    const float* __restrict__ fh,
    const int* __restrict__ fp, int* __restrict__ fn,
    float4* cols, int* s_any) {

    const int BX = tile >> 6, BY = (tile >> 3) & 7, BZ = tile & 7;
    const int lx = t >> 4, ly = t & 15;            // thread = one (x,y) column
    const int gx = BX * 8 - 4 + lx, gy = BY * 8 - 4 + ly;
    const int oz = BZ * 8 - 4;
    const bool xyin = (gx >= 0) & (gx < 64) & (gy >= 0) & (gy < 64);
    const int rowbase = (xyin ? (gx * 64 + gy) * 64 : 0);
    const bool writer = (lx >= 4) & (lx <= 11) & (ly >= 4) & (ly <= 11);

    __syncthreads();               // guard LDS reuse from previous tile
    if (t == 0) *s_any = 0;
    __syncthreads();
    if (t < 27) {
        int dx = t / 9 - 1, dy = (t / 3) % 3 - 1, dz = t % 3 - 1;
        int nx = BX + dx, ny = BY + dy, nz = BZ + dz;
        if (nx >= 0 && nx < 8 && ny >= 0 && ny < 8 && nz >= 0 && nz < 8)
            if (fp[(nx << 6) | (ny << 3) | nz]) atomicOr(s_any, 1);
    }
    __syncthreads();
    const int active = *s_any;

    if (!active) {                 // neighborhood quiet: tile unchanged
        if (writer) {
            *(float4*)&dst[rowbase + oz + 4] = *(const float4*)&src[rowbase + oz + 4];
            *(float4*)&dst[rowbase + oz + 8] = *(const float4*)&src[rowbase + oz + 8];
        }
        if (t == 0) fn[tile] = 0;
        return;
    }

    const int moz = -oz, mzt = 63 - oz;
    const bool zin0 = (oz >= 0), zin3 = (oz + 12 <= 60);
    const int cgx = min(max(gx, 0), 63), cgy = min(max(gy, 0), 63);
    const int fb = (cgx * 64 + cgy) * 64;
    const float4 f0 = *(const float4*)&fh[fb + max(oz, 0)];
    const float4 f1 = *(const float4*)&fh[fb + oz + 4];
    const float4 f2 = *(const float4*)&fh[fb + oz + 8];
    const float4 f3 = *(const float4*)&fh[fb + min(oz + 12, 60)];
    const float4 PAD4 = make_float4(PADV, PADV, PADV, PADV);

    float4 cc0 = (xyin && zin0) ? *(const float4*)&src[rowbase + oz]      : PAD4;
    float4 cc1 = xyin           ? *(const float4*)&src[rowbase + oz + 4]  : PAD4;
    float4 cc2 = xyin           ? *(const float4*)&src[rowbase + oz + 8]  : PAD4;
    float4 cc3 = (xyin && zin3) ? *(const float4*)&src[rowbase + oz + 12] : PAD4;
    const float4 st1 = cc1, st2 = cc2;

    #pragma unroll 1
    for (int it = 0; it < 4; ++it) {
        cols[t] = cc0; cols[256 + t] = cc1;
        cols[512 + t] = cc2; cols[768 + t] = cc3;
        __syncthreads();
        const int s0 = it + 1, s1v = 14 - it;
        if ((lx >= s0) & (lx <= s1v) & (ly >= s0) & (ly <= s1v) & xyin) {
            const int zlo = max(s0, moz), zhi = min(s1v, mzt);
            float4 n, axm, axp, aym, ayp;
            float pw;
            // chunk 0
            axm = cols[t - 16]; axp = cols[t + 16];
            aym = cols[t - 1];  ayp = cols[t + 1];
            n = upd_chunk(cc0, axm, axp, aym, ayp, cc0.x, cc1.x, f0, 0, zlo, zhi);
            pw = cc0.w; cc0 = n;
            // chunk 1
            axm = cols[256 + t - 16]; axp = cols[256 + t + 16];
            aym = cols[256 + t - 1];  ayp = cols[256 + t + 1];
            n = upd_chunk(cc1, axm, axp, aym, ayp, pw, cc2.x, f1, 4, zlo, zhi);
            pw = cc1.w; cc1 = n;
            // chunk 2
            axm = cols[512 + t - 16]; axp = cols[512 + t + 16];
            aym = cols[512 + t - 1];  ayp = cols[512 + t + 1];
            n = upd_chunk(cc2, axm, axp, aym, ayp, pw, cc3.x, f2, 8, zlo, zhi);
            pw = cc2.w; cc2 = n;
            // chunk 3
            axm = cols[768 + t - 16]; axp = cols[768 + t + 16];
            aym = cols[768 + t - 1];  ayp = cols[768 + t + 1];
            n = upd_chunk(cc3, axm, axp, aym, ayp, pw, cc3.w, f3, 12, zlo, zhi);
            cc3 = n;
        }
        __syncthreads();
    }

    if (t == 0) *s_any = 0;
    __syncthreads();
    int chg = 0;
    if (writer) {
        *(float4*)&dst[rowbase + oz + 4] = cc1;
        *(float4*)&dst[rowbase + oz + 8] = cc2;
        chg = (cc1.x != st1.x) | (cc1.y != st1.y) | (cc1.z != st1.z) | (cc1.w != st1.w) |
              (cc2.x != st2.x) | (cc2.y != st2.y) | (cc2.z != st2.z) | (cc2.w != st2.w);
    }
    if (__any(chg) && (t & 63) == 0) atomicOr(s_any, 1);
    __syncthreads();
    if (t == 0) fn[tile] = *s_any;
}

__global__ __launch_bounds__(256) void eik_init(const float* __restrict__ vp,
                                                const float* __restrict__ st,
                                                float* __restrict__ u,
                                                float* __restrict__ fh,
                                                int* __restrict__ flA,
                                                int* __restrict__ cnt) {
    int idx = blockIdx.x * blockDim.x + threadIdx.x;
    if (idx >= NPTS) return;
    float v = vp[idx];
    fh[idx] = 1.0f / v;

    if (idx < NTILE) flA[idx] = 1;   // everyone computes in phase 0
    if (idx < 64) cnt[idx] = 0;      // re-zero barrier counters every launch

    int z = idx & 63;
    int y = (idx >> 6) & 63;
    int x = idx >> 12;

    float sx = st[0], sy = st[1], sz = st[2];
    int ix0 = min(max((int)floorf(sx), 0), 62);
    int iy0 = min(max((int)floorf(sy), 0), 62);
    int iz0 = min(max((int)floorf(sz), 0), 62);
    float xs = fminf(fmaxf(sx, 0.0f), 63.0f);
    float ys = fminf(fmaxf(sy, 0.0f), 63.0f);
    float zs = fminf(fmaxf(sz, 0.0f), 63.0f);

    float val = BIGV;
    if (x >= ix0 && x <= ix0 + 1 && y >= iy0 && y <= iy0 + 1 &&
        z >= iz0 && z <= iz0 + 1) {
        float dx = xs - (float)x;
        float dy = ys - (float)y;
        float dz = zs - (float)z;
        val = sqrtf(dx * dx + dy * dy + dz * dz) / v;
    }
    u[idx] = val;
}

__device__ __forceinline__ void grid_barrier(int* cnt, int g, int tid, int G) {
    __threadfence();
    __syncthreads();
    if (tid == 0) {
        __hip_atomic_fetch_add(&cnt[g], 1, __ATOMIC_RELEASE, __HIP_MEMORY_SCOPE_AGENT);
        while (__hip_atomic_load(&cnt[g], __ATOMIC_ACQUIRE, __HIP_MEMORY_SCOPE_AGENT) < G)
            __builtin_amdgcn_s_sleep(2);
    }
    __syncthreads();
    __threadfence();
}

__global__ __launch_bounds__(256) void eik_persist(
    float* __restrict__ uA, float* __restrict__ uB, const float* __restrict__ fh,
    int* __restrict__ flA, int* __restrict__ flB, int* __restrict__ cnt,
    float* __restrict__ partial,
    const float* __restrict__ evloc, const float* __restrict__ evtime,
    const float* __restrict__ phtime, float* __restrict__ out) {
    __shared__ float4 cols[1024];   // 16 KB column plane
    __shared__ int s_any;
    __shared__ float s_red[4];

    const int b = blockIdx.x;
    const int t = threadIdx.x;
    const int G = gridDim.x;

    for (int g = 0; g < NPH; ++g) {
        const float* src = (g & 1) ? uB : uA;
        float*       dst = (g & 1) ? uA : uB;
        const int*   fp  = (g & 1) ? flB : flA;
        int*         fn  = (g & 1) ? flA : flB;
        for (int tile = b; tile < NTILE; tile += G)
            process_tile(tile, t, src, dst, fh, fp, fn, cols, &s_any);
        grid_barrier(cnt, g, t, G);
    }

    // ---- finalize: interp + loss on final field (uA after 32 phases) ----
    const float* u = uA;
    int gtid = b * 256 + t;
    float psum = 0.0f;
    if (gtid < NEV) {
        int i = gtid;
        float x = evloc[3 * i + 0];
        float y = evloc[3 * i + 1];
        float z = evloc[3 * i + 2];
        int ix0 = min(max((int)floorf(x), 0), 62);
        int iy0 = min(max((int)floorf(y), 0), 62);
        int iz0 = min(max((int)floorf(z), 0), 62);
        float xs = fminf(fmaxf(x, 0.0f), 63.0f);
        float ys = fminf(fmaxf(y, 0.0f), 63.0f);
        float zs = fminf(fmaxf(z, 0.0f), 63.0f);
        float wx0 = xs - (float)ix0, wx1 = (float)(ix0 + 1) - xs;
        float wy0 = ys - (float)iy0, wy1 = (float)(iy0 + 1) - ys;
        float wz0 = zs - (float)iz0, wz1 = (float)(iz0 + 1) - zs;
        int base = ix0 * 4096 + iy0 * 64 + iz0;
        float tt = u[base]             * wx1 * wy1 * wz1 + u[base + 4096]          * wx0 * wy1 * wz1
                 + u[base + 64]        * wx1 * wy0 * wz1 + u[base + 4096 + 64]     * wx0 * wy0 * wz1
                 + u[base + 1]         * wx1 * wy1 * wz0 + u[base + 4096 + 1]      * wx0 * wy1 * wz0
                 + u[base + 64 + 1]    * wx1 * wy0 * wz0 + u[base + 4096 + 64 + 1] * wx0 * wy0 * wz0;
        float at = evtime[i] + tt;
        out[i] = at;
        float d = at - phtime[i];
        psum = d * d;
    }
    #pragma unroll
    for (int off = 32; off > 0; off >>= 1) psum += __shfl_down(psum, off);
    if ((t & 63) == 0) s_red[t >> 6] = psum;
    __syncthreads();
    if (t == 0) partial[b] = s_red[0] + s_red[1] + s_red[2] + s_red[3];

    grid_barrier(cnt, NPH, t, G);

    if (b == 0) {
        float v = 0.0f;
        for (int i = t; i < G; i += 256) v += partial[i];
        #pragma unroll
        for (int off = 32; off > 0; off >>= 1) v += __shfl_down(v, off);
        if ((t & 63) == 0) s_red[t >> 6] = v;
        __syncthreads();
        if (t == 0)
            out[NEV] = (s_red[0] + s_red[1] + s_red[2] + s_red[3]) * (1.0f / (float)NEV);
    }
}

// ---- fallback multi-launch path (same slim body) ----
__global__ __launch_bounds__(256) void eik_group(
    const float* __restrict__ src, float* __restrict__ dst,
    const float* __restrict__ fh,
    const int* __restrict__ fp, int* __restrict__ fn) {
    __shared__ float4 cols[1024];
    __shared__ int s_any;
    process_tile(blockIdx.x, threadIdx.x, src, dst, fh, fp, fn, cols, &s_any);
}

__global__ __launch_bounds__(1024) void eik_finalize(const float* __restrict__ u,
                                                     const float* __restrict__ evloc,
                                                     const float* __restrict__ evtime,
                                                     const float* __restrict__ phtime,
                                                     float* __restrict__ out) {
    __shared__ float red[16];
    int t = threadIdx.x;
    float acc = 0.0f;
    for (int i = t; i < NEV; i += 1024) {
        float x = evloc[3 * i + 0];
        float y = evloc[3 * i + 1];
        float z = evloc[3 * i + 2];
        int ix0 = min(max((int)floorf(x), 0), 62);
        int iy0 = min(max((int)floorf(y), 0), 62);
        int iz0 = min(max((int)floorf(z), 0), 62);
        float xs = fminf(fmaxf(x, 0.0f), 63.0f);
        float ys = fminf(fmaxf(y, 0.0f), 63.0f);
        float zs = fminf(fmaxf(z, 0.0f), 63.0f);
        float wx0 = xs - (float)ix0, wx1 = (float)(ix0 + 1) - xs;
        float wy0 = ys - (float)iy0, wy1 = (float)(iy0 + 1) - ys;
        float wz0 = zs - (float)iz0, wz1 = (float)(iz0 + 1) - zs;
        int base = ix0 * 4096 + iy0 * 64 + iz0;
        float tt = u[base]             * wx1 * wy1 * wz1 + u[base + 4096]          * wx0 * wy1 * wz1
                 + u[base + 64]        * wx1 * wy0 * wz1 + u[base + 4096 + 64]     * wx0 * wy0 * wz1
                 + u[base + 1]         * wx1 * wy1 * wz0 + u[base + 4096 + 1]      * wx0 * wy1 * wz0
                 + u[base + 64 + 1]    * wx1 * wy0 * wz0 + u[base + 4096 + 64 + 1] * wx0 * wy0 * wz0;
        float at = evtime[i] + tt;
        out[i] = at;
        float d = at - phtime[i];
        acc += d * d;
    }
    #pragma unroll
    for (int off = 32; off > 0; off >>= 1) acc += __shfl_down(acc, off);
    if ((t & 63) == 0) red[t >> 6] = acc;
    __syncthreads();
    if (t < 16) {
        float v = red[t];
        #pragma unroll
        for (int off = 8; off > 0; off >>= 1) v += __shfl_down(v, off);
        if (t == 0) out[NEV] = v * (1.0f / (float)NEV);
    }
}

extern "C" void kernel_launch(void* const* d_in, const int* in_sizes, int n_in,
                              void* d_out, int out_size, void* d_ws, size_t ws_size,
                              hipStream_t stream) {
    const float* vp     = (const float*)d_in[0];
    const float* stloc  = (const float*)d_in[1];
    const float* evloc  = (const float*)d_in[2];
    const float* evtime = (const float*)d_in[3];
    const float* phtime = (const float*)d_in[4];
    float* out = (float*)d_out;

    float* w  = (float*)d_ws;
    float* uA = w;                   // 64^3
    float* uB = w + NPTS;            // 64^3
    float* fh = w + 2 * NPTS;        // 64^3
    int* flA  = (int*)(w + 3 * NPTS);
    int* flB  = flA + NTILE;
    int* cnt  = flB + NTILE;         // 64 barrier counters
    float* partial = (float*)(cnt + 64);  // up to 512 partial sums

    eik_init<<<NPTS / 256, 256, 0, stream>>>(vp, stloc, uA, fh, flA, cnt);

    void* kargs[] = { &uA, &uB, &fh, &flA, &flB, &cnt, &partial,
                      (void*)&evloc, (void*)&evtime, (void*)&phtime, &out };
    hipError_t ce = hipLaunchCooperativeKernel(
        reinterpret_cast<void*>(eik_persist), dim3(NTILE), dim3(256), kargs, 0, stream);
    if (ce != hipSuccess)
        ce = hipLaunchCooperativeKernel(
            reinterpret_cast<void*>(eik_persist), dim3(256), dim3(256), kargs, 0, stream);
    if (ce != hipSuccess) {
        // fallback: guaranteed-coherent multi-launch path
        for (int g = 0; g < NPH; ++g) {
            const float* s = (g & 1) ? uB : uA;
            float*       d = (g & 1) ? uA : uB;
            const int*  fp = (g & 1) ? flB : flA;
            int*        fn = (g & 1) ? flA : flB;
            eik_group<<<NTILE, 256, 0, stream>>>(s, d, fh, fp, fn);
        }
        eik_finalize<<<1, 1024, 0, stream>>>(uA, evloc, evtime, phtime, out);
    }
}

// Round 6
// 701.088 us; speedup vs baseline: 9.3008x; 9.3008x over previous
//
#include <hip/hip_runtime.h>
#include <hip/hip_bf16.h>

// Eikonal3D: 64^3 grid, 128 Jacobi Godunov sweeps = 32 launches x 4 fused
// iterations (k=4 temporal blocking, 8^3 tiles, 16^3 halo regions).
// Round 5: slim low-VGPR body (sequential per-chunk updates; VGPR=68 per
// round-4 rocprof) on the guaranteed-coherent MULTI-LAUNCH path. The
// cooperative persistent path is abandoned: round-4 counters showed its
// agent-scope barrier fences cost ~200us/phase (invalidate storms,
// 82MB refetch/dispatch) on multi-XCD CDNA4.
// Monotone-convergence skip flags (27-neighborhood) keep exact Jacobi-128
// semantics while skipping quiet tiles.
// n_iter fixed at 128 by setup_inputs (host must know launch count).

#define NPTS (64 * 64 * 64)
#define BIGV 1000.0f
#define PADV 10000.0f   // BIG*10 pad value
#define NEV 4096
#define NTILE 512       // 8^3 tiles of 8^3 cells
#define NPH 32          // 128 / 4

__device__ __forceinline__ float godunov_cell(float uc, float ax, float ay,
                                              float az, float f) {
    float lo = fminf(ax, ay), hi = fmaxf(ax, ay);
    float a1 = fminf(lo, az);
    float a3 = fmaxf(hi, az);
    float a2 = fminf(fmaxf(lo, az), hi);
    float x1 = a1 + f;
    float d12 = a1 - a2;
    float d2 = 2.0f * f * f - d12 * d12;
    float x2 = 0.5f * (a1 + a2 + sqrtf(fmaxf(d2, 0.0f)));
    float s = a1 + a2 + a3;
    float q = a1 * a1 + a2 * a2 + a3 * a3;
    float d3 = s * s - 3.0f * (q - f * f);
    float x3 = (s + sqrtf(fmaxf(d3, 0.0f))) * (1.0f / 3.0f);
    float unew = (x1 <= a2) ? x1 : ((x2 <= a3) ? x2 : x3);
    return fminf(uc, unew);
}

// one z-chunk (4 cells) Jacobi update; merge via per-element z-range mask
__device__ __forceinline__ float4 upd_chunk(float4 cc, float4 xm, float4 xp,
                                            float4 ym, float4 yp,
                                            float zprev, float znext, float4 f,
                                            int zb, int zlo, int zhi) {
    float n0 = godunov_cell(cc.x, fminf(xm.x, xp.x), fminf(ym.x, yp.x), fminf(zprev, cc.y), f.x);
    float n1 = godunov_cell(cc.y, fminf(xm.y, xp.y), fminf(ym.y, yp.y), fminf(cc.x, cc.z), f.y);
    float n2 = godunov_cell(cc.z, fminf(xm.z, xp.z), fminf(ym.z, yp.z), fminf(cc.y, cc.w), f.z);
    float n3 = godunov_cell(cc.w, fminf(xm.w, xp.w), fminf(ym.w, yp.w), fminf(cc.z, znext), f.w);
    float4 r;
    r.x = (zb + 0 >= zlo && zb + 0 <= zhi) ? n0 : cc.x;
    r.y = (zb + 1 >= zlo && zb + 1 <= zhi) ? n1 : cc.y;
    r.z = (zb + 2 >= zlo && zb + 2 <= zhi) ? n2 : cc.z;
    r.w = (zb + 3 >= zlo && zb + 3 <= zhi) ? n3 : cc.w;
    return r;
}

__global__ __launch_bounds__(256) void eik_init(const float* __restrict__ vp,
                                                const float* __restrict__ st,
                                                float* __restrict__ u,
                                                float* __restrict__ fh,
                                                int* __restrict__ flA) {
    int idx = blockIdx.x * blockDim.x + threadIdx.x;
    if (idx >= NPTS) return;
    float v = vp[idx];
    fh[idx] = 1.0f / v;

    if (idx < NTILE) flA[idx] = 1;   // everyone computes in phase 0

    int z = idx & 63;
    int y = (idx >> 6) & 63;
    int x = idx >> 12;

    float sx = st[0], sy = st[1], sz = st[2];
    int ix0 = min(max((int)floorf(sx), 0), 62);
    int iy0 = min(max((int)floorf(sy), 0), 62);
    int iz0 = min(max((int)floorf(sz), 0), 62);
    float xs = fminf(fmaxf(sx, 0.0f), 63.0f);
    float ys = fminf(fmaxf(sy, 0.0f), 63.0f);
    float zs = fminf(fmaxf(sz, 0.0f), 63.0f);

    float val = BIGV;
    if (x >= ix0 && x <= ix0 + 1 && y >= iy0 && y <= iy0 + 1 &&
        z >= iz0 && z <= iz0 + 1) {
        float dx = xs - (float)x;
        float dy = ys - (float)y;
        float dz = zs - (float)z;
        val = sqrtf(dx * dx + dy * dy + dz * dz) / v;
    }
    u[idx] = val;
}

__global__ __launch_bounds__(256) void eik_group(
    const float* __restrict__ src, float* __restrict__ dst,
    const float* __restrict__ fh,
    const int* __restrict__ fp, int* __restrict__ fn) {
    __shared__ float4 cols[1024];   // 16 KB column plane
    __shared__ int s_any;

    const int tile = blockIdx.x;
    const int t = threadIdx.x;
    const int BX = tile >> 6, BY = (tile >> 3) & 7, BZ = tile & 7;
    const int lx = t >> 4, ly = t & 15;            // thread = one (x,y) column
    const int gx = BX * 8 - 4 + lx, gy = BY * 8 - 4 + ly;
    const int oz = BZ * 8 - 4;
    const bool xyin = (gx >= 0) & (gx < 64) & (gy >= 0) & (gy < 64);
    const int rowbase = (xyin ? (gx * 64 + gy) * 64 : 0);
    const bool writer = (lx >= 4) & (lx <= 11) & (ly >= 4) & (ly <= 11);

    if (t == 0) s_any = 0;
    __syncthreads();
    if (t < 27) {
        int dx = t / 9 - 1, dy = (t / 3) % 3 - 1, dz = t % 3 - 1;
        int nx = BX + dx, ny = BY + dy, nz = BZ + dz;
        if (nx >= 0 && nx < 8 && ny >= 0 && ny < 8 && nz >= 0 && nz < 8)
            if (fp[(nx << 6) | (ny << 3) | nz]) atomicOr(&s_any, 1);
    }
    __syncthreads();
    const int active = s_any;

    if (!active) {                 // neighborhood quiet: tile unchanged
        if (writer) {
            *(float4*)&dst[rowbase + oz + 4] = *(const float4*)&src[rowbase + oz + 4];
            *(float4*)&dst[rowbase + oz + 8] = *(const float4*)&src[rowbase + oz + 8];
        }
        if (t == 0) fn[tile] = 0;
        return;
    }

    const int moz = -oz, mzt = 63 - oz;
    const bool zin0 = (oz >= 0), zin3 = (oz + 12 <= 60);
    const int cgx = min(max(gx, 0), 63), cgy = min(max(gy, 0), 63);
    const int fb = (cgx * 64 + cgy) * 64;
    const float4 f0 = *(const float4*)&fh[fb + max(oz, 0)];
    const float4 f1 = *(const float4*)&fh[fb + oz + 4];
    const float4 f2 = *(const float4*)&fh[fb + oz + 8];
    const float4 f3 = *(const float4*)&fh[fb + min(oz + 12, 60)];
    const float4 PAD4 = make_float4(PADV, PADV, PADV, PADV);

    float4 cc0 = (xyin && zin0) ? *(const float4*)&src[rowbase + oz]      : PAD4;
    float4 cc1 = xyin           ? *(const float4*)&src[rowbase + oz + 4]  : PAD4;
    float4 cc2 = xyin           ? *(const float4*)&src[rowbase + oz + 8]  : PAD4;
    float4 cc3 = (xyin && zin3) ? *(const float4*)&src[rowbase + oz + 12] : PAD4;
    const float4 st1 = cc1, st2 = cc2;

    #pragma unroll 1
    for (int it = 0; it < 4; ++it) {
        cols[t] = cc0; cols[256 + t] = cc1;
        cols[512 + t] = cc2; cols[768 + t] = cc3;
        __syncthreads();
        const int s0 = it + 1, s1v = 14 - it;
        if ((lx >= s0) & (lx <= s1v) & (ly >= s0) & (ly <= s1v) & xyin) {
            const int zlo = max(s0, moz), zhi = min(s1v, mzt);
            float4 n, axm, axp, aym, ayp;
            float pw;
            // chunk 0
            axm = cols[t - 16]; axp = cols[t + 16];
            aym = cols[t - 1];  ayp = cols[t + 1];
            n = upd_chunk(cc0, axm, axp, aym, ayp, cc0.x, cc1.x, f0, 0, zlo, zhi);
            pw = cc0.w; cc0 = n;
            // chunk 1
            axm = cols[256 + t - 16]; axp = cols[256 + t + 16];
            aym = cols[256 + t - 1];  ayp = cols[256 + t + 1];
            n = upd_chunk(cc1, axm, axp, aym, ayp, pw, cc2.x, f1, 4, zlo, zhi);
            pw = cc1.w; cc1 = n;
            // chunk 2
            axm = cols[512 + t - 16]; axp = cols[512 + t + 16];
            aym = cols[512 + t - 1];  ayp = cols[512 + t + 1];
            n = upd_chunk(cc2, axm, axp, aym, ayp, pw, cc3.x, f2, 8, zlo, zhi);
            pw = cc2.w; cc2 = n;
            // chunk 3
            axm = cols[768 + t - 16]; axp = cols[768 + t + 16];
            aym = cols[768 + t - 1];  ayp = cols[768 + t + 1];
            n = upd_chunk(cc3, axm, axp, aym, ayp, pw, cc3.w, f3, 12, zlo, zhi);
            cc3 = n;
        }
        __syncthreads();
    }

    if (t == 0) s_any = 0;
    __syncthreads();
    int chg = 0;
    if (writer) {
        *(float4*)&dst[rowbase + oz + 4] = cc1;
        *(float4*)&dst[rowbase + oz + 8] = cc2;
        chg = (cc1.x != st1.x) | (cc1.y != st1.y) | (cc1.z != st1.z) | (cc1.w != st1.w) |
              (cc2.x != st2.x) | (cc2.y != st2.y) | (cc2.z != st2.z) | (cc2.w != st2.w);
    }
    if (__any(chg) && (t & 63) == 0) atomicOr(&s_any, 1);
    __syncthreads();
    if (t == 0) fn[tile] = s_any;
}

__global__ __launch_bounds__(1024) void eik_finalize(const float* __restrict__ u,
                                                     const float* __restrict__ evloc,
                                                     const float* __restrict__ evtime,
                                                     const float* __restrict__ phtime,
                                                     float* __restrict__ out) {
    __shared__ float red[16];
    int t = threadIdx.x;
    float acc = 0.0f;
    for (int i = t; i < NEV; i += 1024) {
        float x = evloc[3 * i + 0];
        float y = evloc[3 * i + 1];
        float z = evloc[3 * i + 2];
        int ix0 = min(max((int)floorf(x), 0), 62);
        int iy0 = min(max((int)floorf(y), 0), 62);
        int iz0 = min(max((int)floorf(z), 0), 62);
        float xs = fminf(fmaxf(x, 0.0f), 63.0f);
        float ys = fminf(fmaxf(y, 0.0f), 63.0f);
        float zs = fminf(fmaxf(z, 0.0f), 63.0f);
        float wx0 = xs - (float)ix0, wx1 = (float)(ix0 + 1) - xs;
        float wy0 = ys - (float)iy0, wy1 = (float)(iy0 + 1) - ys;
        float wz0 = zs - (float)iz0, wz1 = (float)(iz0 + 1) - zs;
        int base = ix0 * 4096 + iy0 * 64 + iz0;
        float tt = u[base]             * wx1 * wy1 * wz1 + u[base + 4096]          * wx0 * wy1 * wz1
                 + u[base + 64]        * wx1 * wy0 * wz1 + u[base + 4096 + 64]     * wx0 * wy0 * wz1
                 + u[base + 1]         * wx1 * wy1 * wz0 + u[base + 4096 + 1]      * wx0 * wy1 * wz0
                 + u[base + 64 + 1]    * wx1 * wy0 * wz0 + u[base + 4096 + 64 + 1] * wx0 * wy0 * wz0;
        float at = evtime[i] + tt;
        out[i] = at;
        float d = at - phtime[i];
        acc += d * d;
    }
    #pragma unroll
    for (int off = 32; off > 0; off >>= 1) acc += __shfl_down(acc, off);
    if ((t & 63) == 0) red[t >> 6] = acc;
    __syncthreads();
    if (t < 16) {
        float v = red[t];
        #pragma unroll
        for (int off = 8; off > 0; off >>= 1) v += __shfl_down(v, off);
        if (t == 0) out[NEV] = v * (1.0f / (float)NEV);
    }
}

extern "C" void kernel_launch(void* const* d_in, const int* in_sizes, int n_in,
                              void* d_out, int out_size, void* d_ws, size_t ws_size,
                              hipStream_t stream) {
    const float* vp     = (const float*)d_in[0];
    const float* stloc  = (const float*)d_in[1];
    const float* evloc  = (const float*)d_in[2];
    const float* evtime = (const float*)d_in[3];
    const float* phtime = (const float*)d_in[4];
    float* out = (float*)d_out;

    float* w  = (float*)d_ws;
    float* uA = w;                   // 64^3
    float* uB = w + NPTS;            // 64^3
    float* fh = w + 2 * NPTS;        // 64^3
    int* flA  = (int*)(w + 3 * NPTS);
    int* flB  = flA + NTILE;

    eik_init<<<NPTS / 256, 256, 0, stream>>>(vp, stloc, uA, fh, flA);

    for (int g = 0; g < NPH; ++g) {
        const float* s = (g & 1) ? uB : uA;
        float*       d = (g & 1) ? uA : uB;
        const int*  fp = (g & 1) ? flB : flA;
        int*        fn = (g & 1) ? flA : flB;
        eik_group<<<NTILE, 256, 0, stream>>>(s, d, fh, fp, fn);
    }
    // 32 phases (even) -> final field in uA

    eik_finalize<<<1, 1024, 0, stream>>>(uA, evloc, evtime, phtime, out);
}

// Round 7
// 607.528 us; speedup vs baseline: 10.7332x; 1.1540x over previous
//
#include <hip/hip_runtime.h>
#include <hip/hip_bf16.h>

// Eikonal3D: 64^3 grid, 128 Jacobi Godunov sweeps = 32 launches x 4 fused
// iterations (k=4 temporal blocking, 8^3 tiles, 16^3 halo regions).
// Round 6: STRIPPED tile kernel. Rounds 1/3/5 showed ~17-21us/launch for
// three different bodies vs 2.7us for a trivial sweep -> overhead is the
// skip-flag preamble (serial global->LDS-atomic->barrier chain), the
// change-detect tail, and the quiet-copy path, not compute. All removed:
// every block recomputes its tile every phase (exact, same arithmetic),
// 8 barriers/launch instead of 12, fat-ILP neighbor loads.
// n_iter fixed at 128 by setup_inputs (host must know launch count).

#define NPTS (64 * 64 * 64)
#define BIGV 1000.0f
#define PADV 10000.0f   // BIG*10 pad value
#define NEV 4096
#define NTILE 512       // 8^3 tiles of 8^3 cells
#define NPH 32          // 128 / 4

__device__ __forceinline__ float godunov_cell(float uc, float ax, float ay,
                                              float az, float f) {
    float lo = fminf(ax, ay), hi = fmaxf(ax, ay);
    float a1 = fminf(lo, az);
    float a3 = fmaxf(hi, az);
    float a2 = fminf(fmaxf(lo, az), hi);
    float x1 = a1 + f;
    float d12 = a1 - a2;
    float d2 = 2.0f * f * f - d12 * d12;
    float x2 = 0.5f * (a1 + a2 + sqrtf(fmaxf(d2, 0.0f)));
    float s = a1 + a2 + a3;
    float q = a1 * a1 + a2 * a2 + a3 * a3;
    float d3 = s * s - 3.0f * (q - f * f);
    float x3 = (s + sqrtf(fmaxf(d3, 0.0f))) * (1.0f / 3.0f);
    float unew = (x1 <= a2) ? x1 : ((x2 <= a3) ? x2 : x3);
    return fminf(uc, unew);
}

// one z-chunk (4 cells) Jacobi update; merge via per-element z-range mask
__device__ __forceinline__ float4 upd_chunk(float4 cc, float4 xm, float4 xp,
                                            float4 ym, float4 yp,
                                            float zprev, float znext, float4 f,
                                            int zb, int zlo, int zhi) {
    float n0 = godunov_cell(cc.x, fminf(xm.x, xp.x), fminf(ym.x, yp.x), fminf(zprev, cc.y), f.x);
    float n1 = godunov_cell(cc.y, fminf(xm.y, xp.y), fminf(ym.y, yp.y), fminf(cc.x, cc.z), f.y);
    float n2 = godunov_cell(cc.z, fminf(xm.z, xp.z), fminf(ym.z, yp.z), fminf(cc.y, cc.w), f.z);
    float n3 = godunov_cell(cc.w, fminf(xm.w, xp.w), fminf(ym.w, yp.w), fminf(cc.z, znext), f.w);
    float4 r;
    r.x = (zb + 0 >= zlo && zb + 0 <= zhi) ? n0 : cc.x;
    r.y = (zb + 1 >= zlo && zb + 1 <= zhi) ? n1 : cc.y;
    r.z = (zb + 2 >= zlo && zb + 2 <= zhi) ? n2 : cc.z;
    r.w = (zb + 3 >= zlo && zb + 3 <= zhi) ? n3 : cc.w;
    return r;
}

__global__ __launch_bounds__(256) void eik_init(const float* __restrict__ vp,
                                                const float* __restrict__ st,
                                                float* __restrict__ u,
                                                float* __restrict__ fh) {
    int idx = blockIdx.x * blockDim.x + threadIdx.x;
    if (idx >= NPTS) return;
    float v = vp[idx];
    fh[idx] = 1.0f / v;

    int z = idx & 63;
    int y = (idx >> 6) & 63;
    int x = idx >> 12;

    float sx = st[0], sy = st[1], sz = st[2];
    int ix0 = min(max((int)floorf(sx), 0), 62);
    int iy0 = min(max((int)floorf(sy), 0), 62);
    int iz0 = min(max((int)floorf(sz), 0), 62);
    float xs = fminf(fmaxf(sx, 0.0f), 63.0f);
    float ys = fminf(fmaxf(sy, 0.0f), 63.0f);
    float zs = fminf(fmaxf(sz, 0.0f), 63.0f);

    float val = BIGV;
    if (x >= ix0 && x <= ix0 + 1 && y >= iy0 && y <= iy0 + 1 &&
        z >= iz0 && z <= iz0 + 1) {
        float dx = xs - (float)x;
        float dy = ys - (float)y;
        float dz = zs - (float)z;
        val = sqrtf(dx * dx + dy * dy + dz * dz) / v;
    }
    u[idx] = val;
}

__global__ __launch_bounds__(256) void eik_group(
    const float* __restrict__ src, float* __restrict__ dst,
    const float* __restrict__ fh) {
    __shared__ float4 cols[1024];   // 16 KB column plane

    const int tile = blockIdx.x;
    const int BX = tile >> 6, BY = (tile >> 3) & 7, BZ = tile & 7;
    const int t = threadIdx.x;
    const int lx = t >> 4, ly = t & 15;            // thread = one (x,y) column
    const int gx = BX * 8 - 4 + lx, gy = BY * 8 - 4 + ly;
    const int oz = BZ * 8 - 4;
    const bool xyin = (gx >= 0) & (gx < 64) & (gy >= 0) & (gy < 64);
    const int rowbase = (xyin ? (gx * 64 + gy) * 64 : 0);
    const bool writer = (lx >= 4) & (lx <= 11) & (ly >= 4) & (ly <= 11);
    const int moz = -oz, mzt = 63 - oz;
    const bool zin0 = (oz >= 0), zin3 = (oz + 12 <= 60);
    const float4 PAD4 = make_float4(PADV, PADV, PADV, PADV);

    // entry loads at instruction 0: own 16-z column + fh column
    float4 cc0 = (xyin && zin0) ? *(const float4*)&src[rowbase + oz]      : PAD4;
    float4 cc1 = xyin           ? *(const float4*)&src[rowbase + oz + 4]  : PAD4;
    float4 cc2 = xyin           ? *(const float4*)&src[rowbase + oz + 8]  : PAD4;
    float4 cc3 = (xyin && zin3) ? *(const float4*)&src[rowbase + oz + 12] : PAD4;

    const int cgx = min(max(gx, 0), 63), cgy = min(max(gy, 0), 63);
    const int fb = (cgx * 64 + cgy) * 64;
    const float4 f0 = *(const float4*)&fh[fb + max(oz, 0)];
    const float4 f1 = *(const float4*)&fh[fb + oz + 4];
    const float4 f2 = *(const float4*)&fh[fb + oz + 8];
    const float4 f3 = *(const float4*)&fh[fb + min(oz + 12, 60)];

    #pragma unroll
    for (int it = 0; it < 4; ++it) {
        cols[t] = cc0; cols[256 + t] = cc1;
        cols[512 + t] = cc2; cols[768 + t] = cc3;
        __syncthreads();
        const int s0 = it + 1, s1v = 14 - it;
        if ((lx >= s0) & (lx <= s1v) & (ly >= s0) & (ly <= s1v) & xyin) {
            const int zlo = max(s0, moz), zhi = min(s1v, mzt);
            // fat ILP: all 16 neighbor reads issued before compute
            float4 xm0 = cols[t - 16],       xp0 = cols[t + 16];
            float4 ym0 = cols[t - 1],        yp0 = cols[t + 1];
            float4 xm1 = cols[256 + t - 16], xp1 = cols[256 + t + 16];
            float4 ym1 = cols[256 + t - 1],  yp1 = cols[256 + t + 1];
            float4 xm2 = cols[512 + t - 16], xp2 = cols[512 + t + 16];
            float4 ym2 = cols[512 + t - 1],  yp2 = cols[512 + t + 1];
            float4 xm3 = cols[768 + t - 16], xp3 = cols[768 + t + 16];
            float4 ym3 = cols[768 + t - 1],  yp3 = cols[768 + t + 1];
            float4 n0 = upd_chunk(cc0, xm0, xp0, ym0, yp0, cc0.x, cc1.x, f0, 0,  zlo, zhi);
            float4 n1 = upd_chunk(cc1, xm1, xp1, ym1, yp1, cc0.w, cc2.x, f1, 4,  zlo, zhi);
            float4 n2 = upd_chunk(cc2, xm2, xp2, ym2, yp2, cc1.w, cc3.x, f2, 8,  zlo, zhi);
            float4 n3 = upd_chunk(cc3, xm3, xp3, ym3, yp3, cc2.w, cc3.w, f3, 12, zlo, zhi);
            cc0 = n0; cc1 = n1; cc2 = n2; cc3 = n3;
        }
        __syncthreads();
    }

    // write back inner tile (z cells oz+4..oz+11 live in cc1, cc2)
    if (writer) {
        *(float4*)&dst[rowbase + oz + 4] = cc1;
        *(float4*)&dst[rowbase + oz + 8] = cc2;
    }
}

__global__ __launch_bounds__(1024) void eik_finalize(const float* __restrict__ u,
                                                     const float* __restrict__ evloc,
                                                     const float* __restrict__ evtime,
                                                     const float* __restrict__ phtime,
                                                     float* __restrict__ out) {
    __shared__ float red[16];
    int t = threadIdx.x;
    float acc = 0.0f;
    for (int i = t; i < NEV; i += 1024) {
        float x = evloc[3 * i + 0];
        float y = evloc[3 * i + 1];
        float z = evloc[3 * i + 2];
        int ix0 = min(max((int)floorf(x), 0), 62);
        int iy0 = min(max((int)floorf(y), 0), 62);
        int iz0 = min(max((int)floorf(z), 0), 62);
        float xs = fminf(fmaxf(x, 0.0f), 63.0f);
        float ys = fminf(fmaxf(y, 0.0f), 63.0f);
        float zs = fminf(fmaxf(z, 0.0f), 63.0f);
        float wx0 = xs - (float)ix0, wx1 = (float)(ix0 + 1) - xs;
        float wy0 = ys - (float)iy0, wy1 = (float)(iy0 + 1) - ys;
        float wz0 = zs - (float)iz0, wz1 = (float)(iz0 + 1) - zs;
        int base = ix0 * 4096 + iy0 * 64 + iz0;
        float tt = u[base]             * wx1 * wy1 * wz1 + u[base + 4096]          * wx0 * wy1 * wz1
                 + u[base + 64]        * wx1 * wy0 * wz1 + u[base + 4096 + 64]     * wx0 * wy0 * wz1
                 + u[base + 1]         * wx1 * wy1 * wz0 + u[base + 4096 + 1]      * wx0 * wy1 * wz0
                 + u[base + 64 + 1]    * wx1 * wy0 * wz0 + u[base + 4096 + 64 + 1] * wx0 * wy0 * wz0;
        float at = evtime[i] + tt;
        out[i] = at;
        float d = at - phtime[i];
        acc += d * d;
    }
    #pragma unroll
    for (int off = 32; off > 0; off >>= 1) acc += __shfl_down(acc, off);
    if ((t & 63) == 0) red[t >> 6] = acc;
    __syncthreads();
    if (t < 16) {
        float v = red[t];
        #pragma unroll
        for (int off = 8; off > 0; off >>= 1) v += __shfl_down(v, off);
        if (t == 0) out[NEV] = v * (1.0f / (float)NEV);
    }
}

extern "C" void kernel_launch(void* const* d_in, const int* in_sizes, int n_in,
                              void* d_out, int out_size, void* d_ws, size_t ws_size,
                              hipStream_t stream) {
    const float* vp     = (const float*)d_in[0];
    const float* stloc  = (const float*)d_in[1];
    const float* evloc  = (const float*)d_in[2];
    const float* evtime = (const float*)d_in[3];
    const float* phtime = (const float*)d_in[4];
    float* out = (float*)d_out;

    float* w  = (float*)d_ws;
    float* uA = w;                   // 64^3
    float* uB = w + NPTS;            // 64^3
    float* fh = w + 2 * NPTS;        // 64^3

    eik_init<<<NPTS / 256, 256, 0, stream>>>(vp, stloc, uA, fh);

    for (int g = 0; g < NPH; ++g) {
        const float* s = (g & 1) ? uB : uA;
        float*       d = (g & 1) ? uA : uB;
        eik_group<<<NTILE, 256, 0, stream>>>(s, d, fh);
    }
    // 32 phases (even) -> final field in uA

    eik_finalize<<<1, 1024, 0, stream>>>(uA, evloc, evtime, phtime, out);
}

// Round 8
// 490.723 us; speedup vs baseline: 13.2879x; 1.2380x over previous
//
#include <hip/hip_runtime.h>
#include <hip/hip_bf16.h>

// Eikonal3D: 64^3 grid, 128 Jacobi Godunov sweeps = 64 launches of a k=2
// FUSED sweep (each thread computes u_{t+2} of its cell from the 25-point
// diamond-2 stencil: 8 Godunov evals, no LDS, no barriers, 16 waves/CU).
// Rounds 1-6 showed every LDS/barrier tile structure costs 17-20us/launch
// (latency-bound at 2 waves/SIMD) vs 2.7us for barrier-free max-occupancy
// sweeps -- so fewer launches of the cheap structure is the winning lever.
// Bit-exact vs two naive Jacobi sweeps (same godunov_cell expressions).
// n_iter fixed at 128 by setup_inputs (host must know launch count).

#define NPTS (64 * 64 * 64)
#define BIGV 1000.0f
#define PADV 10000.0f   // BIG*10 pad value
#define NEV 4096
#define NSW 64          // 128 / 2

__device__ __forceinline__ float godunov_cell(float uc, float ax, float ay,
                                              float az, float f) {
    float lo = fminf(ax, ay), hi = fmaxf(ax, ay);
    float a1 = fminf(lo, az);
    float a3 = fmaxf(hi, az);
    float a2 = fminf(fmaxf(lo, az), hi);
    float x1 = a1 + f;
    float d12 = a1 - a2;
    float d2 = 2.0f * f * f - d12 * d12;
    float x2 = 0.5f * (a1 + a2 + sqrtf(fmaxf(d2, 0.0f)));
    float s = a1 + a2 + a3;
    float q = a1 * a1 + a2 * a2 + a3 * a3;
    float d3 = s * s - 3.0f * (q - f * f);
    float x3 = (s + sqrtf(fmaxf(d3, 0.0f))) * (1.0f / 3.0f);
    float unew = (x1 <= a2) ? x1 : ((x2 <= a3) ? x2 : x3);
    return fminf(uc, unew);
}

__global__ __launch_bounds__(256) void eik_init(const float* __restrict__ vp,
                                                const float* __restrict__ st,
                                                float* __restrict__ u,
                                                float* __restrict__ fh) {
    int idx = blockIdx.x * blockDim.x + threadIdx.x;
    if (idx >= NPTS) return;
    float v = vp[idx];
    fh[idx] = 1.0f / v;

    int z = idx & 63;
    int y = (idx >> 6) & 63;
    int x = idx >> 12;

    float sx = st[0], sy = st[1], sz = st[2];
    int ix0 = min(max((int)floorf(sx), 0), 62);
    int iy0 = min(max((int)floorf(sy), 0), 62);
    int iz0 = min(max((int)floorf(sz), 0), 62);
    float xs = fminf(fmaxf(sx, 0.0f), 63.0f);
    float ys = fminf(fmaxf(sy, 0.0f), 63.0f);
    float zs = fminf(fmaxf(sz, 0.0f), 63.0f);

    float val = BIGV;
    if (x >= ix0 && x <= ix0 + 1 && y >= iy0 && y <= iy0 + 1 &&
        z >= iz0 && z <= iz0 + 1) {
        float dx = xs - (float)x;
        float dy = ys - (float)y;
        float dz = zs - (float)z;
        val = sqrtf(dx * dx + dy * dy + dz * dz) / v;
    }
    u[idx] = val;
}

// k=2 fused sweep: un = Jacobi^2(u). One thread per cell, no LDS/barriers.
__global__ __launch_bounds__(256) void eik_sweep2(const float* __restrict__ u,
                                                  float* __restrict__ un,
                                                  const float* __restrict__ fh) {
    const int idx = blockIdx.x * blockDim.x + threadIdx.x;
    const int z = idx & 63;
    const int y = (idx >> 6) & 63;
    const int x = idx >> 12;

    // u_{t+1} at in-grid point (px,py,pz); nested loads CSE across calls.
    auto g1 = [&](int px, int py, int pz) -> float {
        const int p = (px * 64 + py) * 64 + pz;
        float uc  = u[p];
        float axm = (px > 0)  ? u[p - 4096] : PADV;
        float axp = (px < 63) ? u[p + 4096] : PADV;
        float aym = (py > 0)  ? u[p - 64]   : PADV;
        float ayp = (py < 63) ? u[p + 64]   : PADV;
        float azm = (pz > 0)  ? u[p - 1]    : PADV;
        float azp = (pz < 63) ? u[p + 1]    : PADV;
        return godunov_cell(uc, fminf(axm, axp), fminf(aym, ayp),
                            fminf(azm, azp), fh[p]);
    };

    float c1  = g1(x, y, z);
    float xm1 = (x > 0)  ? g1(x - 1, y, z) : PADV;
    float xp1 = (x < 63) ? g1(x + 1, y, z) : PADV;
    float ym1 = (y > 0)  ? g1(x, y - 1, z) : PADV;
    float yp1 = (y < 63) ? g1(x, y + 1, z) : PADV;
    float zm1 = (z > 0)  ? g1(x, y, z - 1) : PADV;
    float zp1 = (z < 63) ? g1(x, y, z + 1) : PADV;

    un[idx] = godunov_cell(c1, fminf(xm1, xp1), fminf(ym1, yp1),
                           fminf(zm1, zp1), fh[idx]);
}

__global__ __launch_bounds__(1024) void eik_finalize(const float* __restrict__ u,
                                                     const float* __restrict__ evloc,
                                                     const float* __restrict__ evtime,
                                                     const float* __restrict__ phtime,
                                                     float* __restrict__ out) {
    __shared__ float red[16];
    int t = threadIdx.x;
    float acc = 0.0f;
    for (int i = t; i < NEV; i += 1024) {
        float x = evloc[3 * i + 0];
        float y = evloc[3 * i + 1];
        float z = evloc[3 * i + 2];
        int ix0 = min(max((int)floorf(x), 0), 62);
        int iy0 = min(max((int)floorf(y), 0), 62);
        int iz0 = min(max((int)floorf(z), 0), 62);
        float xs = fminf(fmaxf(x, 0.0f), 63.0f);
        float ys = fminf(fmaxf(y, 0.0f), 63.0f);
        float zs = fminf(fmaxf(z, 0.0f), 63.0f);
        float wx0 = xs - (float)ix0, wx1 = (float)(ix0 + 1) - xs;
        float wy0 = ys - (float)iy0, wy1 = (float)(iy0 + 1) - ys;
        float wz0 = zs - (float)iz0, wz1 = (float)(iz0 + 1) - zs;
        int base = ix0 * 4096 + iy0 * 64 + iz0;
        float tt = u[base]             * wx1 * wy1 * wz1 + u[base + 4096]          * wx0 * wy1 * wz1
                 + u[base + 64]        * wx1 * wy0 * wz1 + u[base + 4096 + 64]     * wx0 * wy0 * wz1
                 + u[base + 1]         * wx1 * wy1 * wz0 + u[base + 4096 + 1]      * wx0 * wy1 * wz0
                 + u[base + 64 + 1]    * wx1 * wy0 * wz0 + u[base + 4096 + 64 + 1] * wx0 * wy0 * wz0;
        float at = evtime[i] + tt;
        out[i] = at;
        float d = at - phtime[i];
        acc += d * d;
    }
    #pragma unroll
    for (int off = 32; off > 0; off >>= 1) acc += __shfl_down(acc, off);
    if ((t & 63) == 0) red[t >> 6] = acc;
    __syncthreads();
    if (t < 16) {
        float v = red[t];
        #pragma unroll
        for (int off = 8; off > 0; off >>= 1) v += __shfl_down(v, off);
        if (t == 0) out[NEV] = v * (1.0f / (float)NEV);
    }
}

extern "C" void kernel_launch(void* const* d_in, const int* in_sizes, int n_in,
                              void* d_out, int out_size, void* d_ws, size_t ws_size,
                              hipStream_t stream) {
    const float* vp     = (const float*)d_in[0];
    const float* stloc  = (const float*)d_in[1];
    const float* evloc  = (const float*)d_in[2];
    const float* evtime = (const float*)d_in[3];
    const float* phtime = (const float*)d_in[4];
    float* out = (float*)d_out;

    float* w  = (float*)d_ws;
    float* uA = w;                   // 64^3
    float* uB = w + NPTS;            // 64^3
    float* fh = w + 2 * NPTS;        // 64^3

    eik_init<<<NPTS / 256, 256, 0, stream>>>(vp, stloc, uA, fh);

    for (int g = 0; g < NSW; ++g) {
        const float* s = (g & 1) ? uB : uA;
        float*       d = (g & 1) ? uA : uB;
        eik_sweep2<<<NPTS / 256, 256, 0, stream>>>(s, d, fh);
    }
    // 64 fused sweeps (even) -> final field in uA

    eik_finalize<<<1, 1024, 0, stream>>>(uA, evloc, evtime, phtime, out);
}

// Round 9
// 452.864 us; speedup vs baseline: 14.3988x; 1.0836x over previous
//
#include <hip/hip_runtime.h>
#include <hip/hip_bf16.h>

// Eikonal3D: 64^3 grid, 128 Jacobi Godunov sweeps = 64 launches of a k=2
// fused sweep, COLUMN-VECTORIZED: each thread owns a 2-cell z-column.
// All global reads are aligned coalesced float2 loads of whole columns
// (30 loads/thread vs ~60 scalar in round 7); u1 evals shared across the
// column (14 evals / 2 cells vs 8/cell scalar); z-neighbors register-local.
// Bit-exact vs two naive Jacobi sweeps. No LDS, no barriers, 2 waves/SIMD.
// Round-7 lesson: scalar k=2 exec ~5us was load/address-arithmetic-bound.
// n_iter fixed at 128 by setup_inputs (host must know launch count).

#define NPTS (64 * 64 * 64)
#define BIGV 1000.0f
#define PADV 10000.0f   // BIG*10 pad value
#define NEV 4096
#define NSW 64          // 128 / 2

__device__ __forceinline__ float godunov_cell(float uc, float ax, float ay,
                                              float az, float f) {
    float lo = fminf(ax, ay), hi = fmaxf(ax, ay);
    float a1 = fminf(lo, az);
    float a3 = fmaxf(hi, az);
    float a2 = fminf(fmaxf(lo, az), hi);
    float x1 = a1 + f;
    float d12 = a1 - a2;
    float d2 = 2.0f * f * f - d12 * d12;
    float x2 = 0.5f * (a1 + a2 + sqrtf(fmaxf(d2, 0.0f)));
    float s = a1 + a2 + a3;
    float q = a1 * a1 + a2 * a2 + a3 * a3;
    float d3 = s * s - 3.0f * (q - f * f);
    float x3 = (s + sqrtf(fmaxf(d3, 0.0f))) * (1.0f / 3.0f);
    float unew = (x1 <= a2) ? x1 : ((x2 <= a3) ? x2 : x3);
    return fminf(uc, unew);
}

// cells z0-2..z0+3 of column at `base` into v[6] (PADV outside grid/column)
__device__ __forceinline__ void load6(const float* __restrict__ u, bool colin,
                                      int base, int z0, int zc, float v[6]) {
    float2 t;
    t = (colin && zc > 0)  ? *(const float2*)&u[base + z0 - 2] : make_float2(PADV, PADV);
    v[0] = t.x; v[1] = t.y;
    t = colin              ? *(const float2*)&u[base + z0]     : make_float2(PADV, PADV);
    v[2] = t.x; v[3] = t.y;
    t = (colin && zc < 31) ? *(const float2*)&u[base + z0 + 2] : make_float2(PADV, PADV);
    v[4] = t.x; v[5] = t.y;
}

__device__ __forceinline__ float2 ld2(const float* __restrict__ u, bool colin,
                                      int base, int z0) {
    return colin ? *(const float2*)&u[base + z0] : make_float2(PADV, PADV);
}

__device__ __forceinline__ float pk(float2 v, int k) { return k == 0 ? v.x : v.y; }

__global__ __launch_bounds__(256) void eik_init(const float* __restrict__ vp,
                                                const float* __restrict__ st,
                                                float* __restrict__ u,
                                                float* __restrict__ fh) {
    int idx = blockIdx.x * blockDim.x + threadIdx.x;
    if (idx >= NPTS) return;
    float v = vp[idx];
    fh[idx] = 1.0f / v;

    int z = idx & 63;
    int y = (idx >> 6) & 63;
    int x = idx >> 12;

    float sx = st[0], sy = st[1], sz = st[2];
    int ix0 = min(max((int)floorf(sx), 0), 62);
    int iy0 = min(max((int)floorf(sy), 0), 62);
    int iz0 = min(max((int)floorf(sz), 0), 62);
    float xs = fminf(fmaxf(sx, 0.0f), 63.0f);
    float ys = fminf(fmaxf(sy, 0.0f), 63.0f);
    float zs = fminf(fmaxf(sz, 0.0f), 63.0f);

    float val = BIGV;
    if (x >= ix0 && x <= ix0 + 1 && y >= iy0 && y <= iy0 + 1 &&
        z >= iz0 && z <= iz0 + 1) {
        float dx = xs - (float)x;
        float dy = ys - (float)y;
        float dz = zs - (float)z;
        val = sqrtf(dx * dx + dy * dy + dz * dz) / v;
    }
    u[idx] = val;
}

// k=2 fused sweep, 2-cell z-columns: un = Jacobi^2(u). 131072 threads.
__global__ __launch_bounds__(256) void eik_sweep2(const float* __restrict__ u,
                                                  float* __restrict__ un,
                                                  const float* __restrict__ fh) {
    const int n = blockIdx.x * 256 + threadIdx.x;
    const int zc = n & 31, z0 = zc * 2;
    const int y = (n >> 5) & 63;
    const int x = n >> 11;
    const int bown = (x * 64 + y) * 64;

    // u0: 6-cell windows of the 5 near columns
    float co[6], cxm[6], cxp[6], cym[6], cyp[6];
    load6(u, true,   bown,        z0, zc, co);
    load6(u, x > 0,  bown - 4096, z0, zc, cxm);
    load6(u, x < 63, bown + 4096, z0, zc, cxp);
    load6(u, y > 0,  bown - 64,   z0, zc, cym);
    load6(u, y < 63, bown + 64,   z0, zc, cyp);

    // u0: 2-cell chunks of the 8 distance-2 xy columns
    float2 xxm = ld2(u, x > 1,             bown - 8192,      z0);
    float2 xxp = ld2(u, x < 62,            bown + 8192,      z0);
    float2 yym = ld2(u, y > 1,             bown - 128,       z0);
    float2 yyp = ld2(u, y < 62,            bown + 128,       z0);
    float2 dmm = ld2(u, (x > 0) & (y > 0),   bown - 4096 - 64, z0);
    float2 dmp = ld2(u, (x > 0) & (y < 63),  bown - 4096 + 64, z0);
    float2 dpm = ld2(u, (x < 63) & (y > 0),  bown + 4096 - 64, z0);
    float2 dpp = ld2(u, (x < 63) & (y < 63), bown + 4096 + 64, z0);

    // fh where u1 is evaluated
    float fo[6];
    load6(fh, true, bown, z0, zc, fo);
    float2 fxm = ld2(fh, x > 0,  bown - 4096, z0);
    float2 fxp = ld2(fh, x < 63, bown + 4096, z0);
    float2 fym = ld2(fh, y > 0,  bown - 64,   z0);
    float2 fyp = ld2(fh, y < 63, bown + 64,   z0);

    // ---- u1 on own column, cells z0-1..z0+2 (window idx 1..4) ----
    float u1o[4];
    #pragma unroll
    for (int i = 1; i <= 4; ++i) {
        int zcell = z0 - 2 + i;
        float val = PADV;
        if (zcell >= 0 && zcell <= 63)
            val = godunov_cell(co[i], fminf(cxm[i], cxp[i]), fminf(cym[i], cyp[i]),
                               fminf(co[i - 1], co[i + 1]), fo[i]);
        u1o[i - 1] = val;
    }

    // ---- u1 on the 4 distance-1 columns, cells z0+k (k=0,1) ----
    float u1xm[2], u1xp[2], u1ym[2], u1yp[2];
    #pragma unroll
    for (int k = 0; k < 2; ++k) {
        float cok = co[2 + k];
        u1xm[k] = (x > 0) ? godunov_cell(cxm[2 + k],
                      fminf(pk(xxm, k), cok),
                      fminf(pk(dmm, k), pk(dmp, k)),
                      fminf(cxm[1 + k], cxm[3 + k]), pk(fxm, k)) : PADV;
        u1xp[k] = (x < 63) ? godunov_cell(cxp[2 + k],
                      fminf(cok, pk(xxp, k)),
                      fminf(pk(dpm, k), pk(dpp, k)),
                      fminf(cxp[1 + k], cxp[3 + k]), pk(fxp, k)) : PADV;
        u1ym[k] = (y > 0) ? godunov_cell(cym[2 + k],
                      fminf(pk(dmm, k), pk(dpm, k)),
                      fminf(pk(yym, k), cok),
                      fminf(cym[1 + k], cym[3 + k]), pk(fym, k)) : PADV;
        u1yp[k] = (y < 63) ? godunov_cell(cyp[2 + k],
                      fminf(pk(dmp, k), pk(dpp, k)),
                      fminf(cok, pk(yyp, k)),
                      fminf(cyp[1 + k], cyp[3 + k]), pk(fyp, k)) : PADV;
    }

    // ---- u2 at own cells z0, z0+1 ----
    float r0 = godunov_cell(u1o[1], fminf(u1xm[0], u1xp[0]), fminf(u1ym[0], u1yp[0]),
                            fminf(u1o[0], u1o[2]), fo[2]);
    float r1 = godunov_cell(u1o[2], fminf(u1xm[1], u1xp[1]), fminf(u1ym[1], u1yp[1]),
                            fminf(u1o[1], u1o[3]), fo[3]);
    *(float2*)&un[bown + z0] = make_float2(r0, r1);
}

__global__ __launch_bounds__(1024) void eik_finalize(const float* __restrict__ u,
                                                     const float* __restrict__ evloc,
                                                     const float* __restrict__ evtime,
                                                     const float* __restrict__ phtime,
                                                     float* __restrict__ out) {
    __shared__ float red[16];
    int t = threadIdx.x;
    float acc = 0.0f;
    for (int i = t; i < NEV; i += 1024) {
        float x = evloc[3 * i + 0];
        float y = evloc[3 * i + 1];
        float z = evloc[3 * i + 2];
        int ix0 = min(max((int)floorf(x), 0), 62);
        int iy0 = min(max((int)floorf(y), 0), 62);
        int iz0 = min(max((int)floorf(z), 0), 62);
        float xs = fminf(fmaxf(x, 0.0f), 63.0f);
        float ys = fminf(fmaxf(y, 0.0f), 63.0f);
        float zs = fminf(fmaxf(z, 0.0f), 63.0f);
        float wx0 = xs - (float)ix0, wx1 = (float)(ix0 + 1) - xs;
        float wy0 = ys - (float)iy0, wy1 = (float)(iy0 + 1) - ys;
        float wz0 = zs - (float)iz0, wz1 = (float)(iz0 + 1) - zs;
        int base = ix0 * 4096 + iy0 * 64 + iz0;
        float tt = u[base]             * wx1 * wy1 * wz1 + u[base + 4096]          * wx0 * wy1 * wz1
                 + u[base + 64]        * wx1 * wy0 * wz1 + u[base + 4096 + 64]     * wx0 * wy0 * wz1
                 + u[base + 1]         * wx1 * wy1 * wz0 + u[base + 4096 + 1]      * wx0 * wy1 * wz0
                 + u[base + 64 + 1]    * wx1 * wy0 * wz0 + u[base + 4096 + 64 + 1] * wx0 * wy0 * wz0;
        float at = evtime[i] + tt;
        out[i] = at;
        float d = at - phtime[i];
        acc += d * d;
    }
    #pragma unroll
    for (int off = 32; off > 0; off >>= 1) acc += __shfl_down(acc, off);
    if ((t & 63) == 0) red[t >> 6] = acc;
    __syncthreads();
    if (t < 16) {
        float v = red[t];
        #pragma unroll
        for (int off = 8; off > 0; off >>= 1) v += __shfl_down(v, off);
        if (t == 0) out[NEV] = v * (1.0f / (float)NEV);
    }
}

extern "C" void kernel_launch(void* const* d_in, const int* in_sizes, int n_in,
                              void* d_out, int out_size, void* d_ws, size_t ws_size,
                              hipStream_t stream) {
    const float* vp     = (const float*)d_in[0];
    const float* stloc  = (const float*)d_in[1];
    const float* evloc  = (const float*)d_in[2];
    const float* evtime = (const float*)d_in[3];
    const float* phtime = (const float*)d_in[4];
    float* out = (float*)d_out;

    float* w  = (float*)d_ws;
    float* uA = w;                   // 64^3
    float* uB = w + NPTS;            // 64^3
    float* fh = w + 2 * NPTS;        // 64^3

    eik_init<<<NPTS / 256, 256, 0, stream>>>(vp, stloc, uA, fh);

    for (int g = 0; g < NSW; ++g) {
        const float* s = (g & 1) ? uB : uA;
        float*       d = (g & 1) ? uA : uB;
        eik_sweep2<<<NPTS / 512, 256, 0, stream>>>(s, d, fh);
    }
    // 64 fused sweeps (even) -> final field in uA

    eik_finalize<<<1, 1024, 0, stream>>>(uA, evloc, evtime, phtime, out);
}